// Round 1
// baseline (118.199 us; speedup 1.0000x reference)
//
#include <hip/hip_runtime.h>
#include <hip/hip_bf16.h>
#include <math.h>

typedef __attribute__((ext_vector_type(4))) float floatx4;

#define MARGIN_C    0.09f
#define ONE_M_EPS   0.99999f
#define NCLS        64
#define MEMSTRIDE   256

__device__ __forceinline__ unsigned short f2bf(float f) {
    unsigned u = __float_as_uint(f);
    u += 0x7fffu + ((u >> 16) & 1u);
    return (unsigned short)(u >> 16);
}
__device__ __forceinline__ float bf2f(unsigned short v) {
    return __uint_as_float(((unsigned)v) << 16);
}
// order-preserving float<->uint key for atomicMax on floats
__device__ __forceinline__ unsigned fkey(float f) {
    unsigned u = __float_as_uint(f);
    return (u >> 31) ? ~u : (u | 0x80000000u);
}
__device__ __forceinline__ float fdec(unsigned k) {
    return __uint_as_float((k >> 31) ? (k & 0x7fffffffu) : ~k);
}
__device__ __forceinline__ void gld16(const void* g, void* l) {
    __builtin_amdgcn_global_load_lds(
        (const __attribute__((address_space(1))) void*)g,
        (__attribute__((address_space(3))) void*)l, 16, 0, 0);
}

// ---------- fused: fp32->fp8 cvt + stat zeroing + out zeroing + member lists
__global__ __launch_bounds__(256) void cvt_build(const float* __restrict__ in,
                                                 unsigned* __restrict__ out8,   // 4 fp8 per uint
                                                 float* __restrict__ statz,     // negsum+negmax
                                                 const int* __restrict__ labels,
                                                 int* __restrict__ members,
                                                 int* __restrict__ classCount,
                                                 float* __restrict__ loss_out,
                                                 int n4, int nz4, int ncvt, int Bn) {
    __shared__ int cnt;
    const int bid = blockIdx.x;
    const int t = threadIdx.x;
    if (bid < ncvt) {
        int i = bid * 256 + t;
        if (bid == 0 && t == 0) loss_out[0] = 0.0f;
        if (i < nz4) ((float4*)statz)[i] = make_float4(0.f, 0.f, 0.f, 0.f);
        if (i >= n4) return;
        float4 v = ((const float4*)in)[i];
        int w = __builtin_amdgcn_cvt_pk_fp8_f32(v.x, v.y, 0, false);   // bytes 0,1
        w = __builtin_amdgcn_cvt_pk_fp8_f32(v.z, v.w, w, true);        // bytes 2,3
        out8[i] = (unsigned)w;
    } else {
        const int c = bid - ncvt;
        if (t == 0) cnt = 0;
        __syncthreads();
        for (int j = t; j < Bn; j += 256) {
            if (labels[j] == c) {
                int p = atomicAdd(&cnt, 1);
                if (p < MEMSTRIDE) members[c * MEMSTRIDE + p] = j;
            }
        }
        __syncthreads();
        if (t == 0) classCount[c] = (cnt < MEMSTRIDE) ? cnt : MEMSTRIDE;
    }
}

// ---------- GEMM, FP8 e4m3, 128x64 tiles (grid 1056 -> 4 blocks/CU) ---------
// R15: 3-deep LDS pipeline with counted vmcnt + raw barriers. The old
// __syncthreads() per stage compiled to s_waitcnt vmcnt(0) -> drained the DMA
// issued at the TOP of the same stage (one compute phase of cover, ~315 cyc,
// vs 200-700 cyc L2/L3 latency). Now: issue DMA(s+2), wait vmcnt(6) (= stage-s
// data landed, 6 loads stay in flight), raw s_barrier, compute, raw s_barrier
// (buf-reuse WAR guard, no drain). Each DMA gets TWO compute phases to land.
// LDS 3x(8K+4K)=36.75KB -> still 4 blocks/CU (147KB<160KB), keeping the
// inter-block m114 overlap. Per-thread vmcnt bookkeeping: 3 gld16/stage,
// steady 9 outstanding after issue, wait to 6; tail 3 then 0.
__global__ __launch_bounds__(256, 4) void gemm_fused(const unsigned char* __restrict__ fb8,
                                                     const int* __restrict__ labels,
                                                     float* __restrict__ negsum,
                                                     unsigned* __restrict__ negmax,
                                                     unsigned short* __restrict__ pairsim,
                                                     int Bn, int Dn) {
    __shared__ __align__(16) unsigned char As[3][8192];   // [128 rows][64B] tri-buf
    __shared__ __align__(16) unsigned char Bs[3][4096];   // [64 rows][64B] tri-buf
    __shared__ int Lrow[128], Lcol[64];

    // bid -> (by, c64): band by starts at by*(by+1), has 2*by+2 tiles
    const int bid = blockIdx.x;
    int by = (int)(sqrtf((float)bid + 0.25f) - 0.5f);
    while ((by + 1) * (by + 2) <= bid) by++;
    while (by * (by + 1) > bid) by--;
    const int c64 = bid - by * (by + 1);
    const int gcb = c64 * 64;                 // global col base
    const bool mirror = (gcb < by * 128);     // strictly left of diag block

    const int t = threadIdx.x;
    const int wave = t >> 6, lane = t & 63;
    const int quad = lane >> 4, m16 = lane & 15;

    if (t < 128) Lrow[t] = labels[by * 128 + t];
    else if (t < 192) Lcol[t - 128] = labels[gcb + (t - 128)];

    // staging: A rows r=t>>2 and r+64 (slot a=t&3); B rows r (64 rows, 1 granule).
    // Global fetch XOR-swizzled so linear-LDS ds_read_b64 frags are conflict-free.
    const int r = t >> 2, a = t & 3;
    const int gofs = ((2 * a) ^ (r & 6)) * 8;
    const unsigned char* gA0 = fb8 + (size_t)(by * 128 + r) * Dn + gofs;
    const unsigned char* gA1 = gA0 + (size_t)64 * Dn;
    const unsigned char* gB0 = fb8 + (size_t)(gcb + r) * Dn + gofs;
    const int lb = t * 16;   // bytes

    floatx4 acc[2][4];
#pragma unroll
    for (int i = 0; i < 2; i++)
#pragma unroll
        for (int j = 0; j < 4; j++) acc[i][j] = (floatx4){0.f, 0.f, 0.f, 0.f};

    // fragment reads: row stride 64B; logical half-chunk hc = quad + 4*kstep
    // lives at physical (hc ^ (m16&6))*8
    const int fragA = (wave * 32 + m16) * 64;
    const int fragB = m16 * 64;
    const int sw = m16 & 6;
    const int sK0 = (quad ^ sw) * 8;
    const int sK1 = ((quad + 4) ^ sw) * 8;

    const int NS = Dn / 64;   // 16 stages

    // prologue: DMA(0) -> buf 0, DMA(1) -> buf 1 (6 gld16/thread in flight)
    gld16(gA0, &As[0][lb]);
    gld16(gA1, &As[0][4096 + lb]);
    gld16(gB0, &Bs[0][lb]);
    if (NS > 1) {
        gld16(gA0 + 64, &As[1][lb]);
        gld16(gA1 + 64, &As[1][4096 + lb]);
        gld16(gB0 + 64, &Bs[1][lb]);
    }
    __builtin_amdgcn_sched_barrier(0);

    int cur = 0;        // buffer holding stage s
    int nb = 2;         // buffer for stage s+2

    for (int s = 0; s < NS; s++) {
        if (s + 2 < NS) {
            const int ko = (s + 2) * 64;
            gld16(gA0 + ko, &As[nb][lb]);
            gld16(gA1 + ko, &As[nb][4096 + lb]);
            gld16(gB0 + ko, &Bs[nb][lb]);
        }
        __builtin_amdgcn_sched_barrier(0);   // pin DMA issue before the wait

        // wait for stage-s data only (counted; never drain mid-loop)
        if (s + 2 < NS)      asm volatile("s_waitcnt vmcnt(6)" ::: "memory");
        else if (s + 1 < NS) asm volatile("s_waitcnt vmcnt(3)" ::: "memory");
        else                 asm volatile("s_waitcnt vmcnt(0)" ::: "memory");
        __builtin_amdgcn_s_barrier();        // all waves' stage-s DMA landed
        __builtin_amdgcn_sched_barrier(0);   // no ds_read hoisting above barrier

        const unsigned char* as_ = &As[cur][0];
        const unsigned char* bs_ = &Bs[cur][0];
        long af[2], bfr[4];
        // k-step 0
#pragma unroll
        for (int i = 0; i < 2; i++) af[i]  = *(const long*)(as_ + fragA + i * 1024 + sK0);
#pragma unroll
        for (int j = 0; j < 4; j++) bfr[j] = *(const long*)(bs_ + fragB + j * 1024 + sK0);
#pragma unroll
        for (int i = 0; i < 2; i++)
#pragma unroll
            for (int j = 0; j < 4; j++)
                acc[i][j] = __builtin_amdgcn_mfma_f32_16x16x32_fp8_fp8(af[i], bfr[j], acc[i][j], 0, 0, 0);
        // k-step 1
#pragma unroll
        for (int i = 0; i < 2; i++) af[i]  = *(const long*)(as_ + fragA + i * 1024 + sK1);
#pragma unroll
        for (int j = 0; j < 4; j++) bfr[j] = *(const long*)(bs_ + fragB + j * 1024 + sK1);
#pragma unroll
        for (int i = 0; i < 2; i++)
#pragma unroll
            for (int j = 0; j < 4; j++)
                acc[i][j] = __builtin_amdgcn_mfma_f32_16x16x32_fp8_fp8(af[i], bfr[j], acc[i][j], 0, 0, 0);

        __builtin_amdgcn_sched_barrier(0);   // reads consumed (lgkm waits precede MFMAs)
        __builtin_amdgcn_s_barrier();        // WAR guard: buf[cur] free for DMA(s+3)
        __builtin_amdgcn_sched_barrier(0);

        cur = (cur == 2) ? 0 : cur + 1;
        nb  = (nb  == 2) ? 0 : nb  + 1;
    }

    // ----- single-pass epilogue (C/D: col = m16 + j*16, row = quad*4+rr + i*16)
    int cl[4], gc[4];
#pragma unroll
    for (int j = 0; j < 4; j++) {
        cl[j] = Lcol[j * 16 + m16];
        gc[j] = gcb + j * 16 + m16;
    }

    float nsm[4] = {0.f, 0.f, 0.f, 0.f};
    float nmm[4] = {-INFINITY, -INFINITY, -INFINITY, -INFINITY};

#pragma unroll
    for (int i = 0; i < 2; i++) {
#pragma unroll
        for (int rr = 0; rr < 4; rr++) {
            const int rowl = wave * 32 + i * 16 + quad * 4 + rr;
            const int rl = Lrow[rowl];
            const int gr = by * 128 + rowl;
            float ns = 0.f, nm = -INFINITY;
#pragma unroll
            for (int j = 0; j < 4; j++) {
                const float s = acc[i][j][rr];
                if (cl[j] != rl) {
                    const float e = __expf(40.f * s);
                    ns += e;
                    nm = fmaxf(nm, s);
                    nsm[j] += e;
                    nmm[j] = fmaxf(nmm[j], s);
                } else if ((gr != gc[j]) & (s < ONE_M_EPS)) {
                    const unsigned short v = f2bf(s);
                    pairsim[(size_t)gr * Bn + gc[j]] = v;
                    if (mirror) pairsim[(size_t)gc[j] * Bn + gr] = v;
                }
            }
#pragma unroll
            for (int o = 8; o; o >>= 1) {
                ns += __shfl_down(ns, o, 64);
                nm = fmaxf(nm, __shfl_down(nm, o, 64));
            }
            if (m16 == 0) {
                atomicAdd(negsum + gr, ns);
                atomicMax(negmax + gr, fkey(nm));
            }
        }
    }
    if (mirror) {   // column stats feed rows gcb.. (only for strictly-left tiles)
#pragma unroll
        for (int j = 0; j < 4; j++) {
            float v = nsm[j], m = nmm[j];
            v += __shfl_down(v, 16, 64);
            m = fmaxf(m, __shfl_down(m, 16, 64));
            v += __shfl_down(v, 32, 64);
            m = fmaxf(m, __shfl_down(m, 32, 64));
            if (quad == 0) {
                atomicAdd(negsum + gc[j], v);
                atomicMax(negmax + gc[j], fkey(m));
            }
        }
    }
}

// ---------- positives + per-row loss + mean, merged (16 rows/block) ---------
__global__ __launch_bounds__(256) void pos_final(const unsigned short* __restrict__ pairsim,
                                                 const int* __restrict__ labels,
                                                 const int* __restrict__ members,
                                                 const int* __restrict__ classCount,
                                                 const unsigned* __restrict__ negmax,
                                                 const float* __restrict__ negsum,
                                                 float* __restrict__ out, int Bn) {
    __shared__ float part[4];
    const int t = threadIdx.x;
    const int wave = t >> 6, lane = t & 63;
    float wacc = 0.f;
#pragma unroll
    for (int rr = 0; rr < 4; rr++) {
        const int r = blockIdx.x * 16 + wave * 4 + rr;
        if (r >= Bn) break;
        const int lab = labels[r];
        const int n = classCount[lab];
        const int base = lab * MEMSTRIDE;
        const float mx = fdec(negmax[r]);
        const unsigned short* prow = pairsim + (size_t)r * Bn;

        float ps = 0.f, pc = 0.f;
        for (int j = lane; j < n; j += 64) {
            const int m = members[base + j];
            if (m != r) {
                const float s = bf2f(prow[m]);
                if ((s - MARGIN_C) < mx) {
                    ps += __expf(-2.f * s);
                    pc += 1.f;
                }
            }
        }
#pragma unroll
        for (int o = 32; o; o >>= 1) {
            ps += __shfl_down(ps, o, 64);
            pc += __shfl_down(pc, o, 64);
        }
        if (lane == 0) {
            const int nneg = Bn - n;
            if (nneg >= 1 && pc >= 0.5f) {
                float pl = 0.5f * logf((ps + expf(-2.f * 0.501f)) / (pc + 1.f));
                float nl = (1.f / 40.f) * logf((negsum[r] + expf(40.f * 0.531f)) / ((float)nneg + 1.f));
                wacc += logf(5.33f + expf(pl + nl));
            }
        }
    }
    if (lane == 0) part[wave] = wacc;
    __syncthreads();
    if (t == 0) {
        atomicAdd(out, (part[0] + part[1] + part[2] + part[3]) / (float)Bn);
    }
}

extern "C" void kernel_launch(void* const* d_in, const int* in_sizes, int n_in,
                              void* d_out, int out_size, void* d_ws, size_t ws_size,
                              hipStream_t stream) {
    const float* feats = (const float*)d_in[0];
    const int* labels  = (const int*)d_in[1];
    float* out = (float*)d_out;

    const int Bn = in_sizes[1];           // 4096
    const int Dn = in_sizes[0] / Bn;      // 1024

    unsigned char* fb8 = (unsigned char*)d_ws;                  // fp8 feats [Bn][Dn]
    float* stats    = (float*)(fb8 + (size_t)Bn * Dn);
    float* negsum   = stats;                                    // [Bn]
    unsigned* negmax = (unsigned*)(stats + Bn);                 // [Bn] keyed
    int* classCount = (int*)(stats + 2 * Bn);                   // [NCLS]
    int* members    = classCount + NCLS;                        // [NCLS][MEMSTRIDE]
    unsigned short* pairsim = (unsigned short*)(members + NCLS * MEMSTRIDE); // [Bn][Bn]

    const int n4   = (Bn * Dn) / 4;
    const int nz4  = (2 * Bn) / 4;        // zero negsum+negmax
    const int ncvt = (n4 + 255) / 256;
    cvt_build<<<ncvt + NCLS, 256, 0, stream>>>(feats, (unsigned*)fb8, stats, labels,
                                               members, classCount, out,
                                               n4, nz4, ncvt, Bn);

    const int nt = Bn / 128;              // 32 bands
    const int ngrid = nt * (nt + 1);      // 1056 tiles of 128x64
    gemm_fused<<<ngrid, 256, 0, stream>>>(fb8, labels, negsum, negmax, pairsim, Bn, Dn);

    pos_final<<<(Bn + 15) / 16, 256, 0, stream>>>(pairsim, labels, members, classCount,
                                                  negmax, negsum, out, Bn);
}

// Round 2
// 114.457 us; speedup vs baseline: 1.0327x; 1.0327x over previous
//
#include <hip/hip_runtime.h>
#include <hip/hip_bf16.h>
#include <math.h>

typedef __attribute__((ext_vector_type(4))) float floatx4;

#define MARGIN_C    0.09f
#define ONE_M_EPS   0.99999f
#define NCLS        64
#define MEMSTRIDE   256

__device__ __forceinline__ unsigned short f2bf(float f) {
    unsigned u = __float_as_uint(f);
    u += 0x7fffu + ((u >> 16) & 1u);
    return (unsigned short)(u >> 16);
}
__device__ __forceinline__ float bf2f(unsigned short v) {
    return __uint_as_float(((unsigned)v) << 16);
}
// order-preserving float<->uint key for atomicMax on floats
__device__ __forceinline__ unsigned fkey(float f) {
    unsigned u = __float_as_uint(f);
    return (u >> 31) ? ~u : (u | 0x80000000u);
}
__device__ __forceinline__ float fdec(unsigned k) {
    return __uint_as_float((k >> 31) ? (k & 0x7fffffffu) : ~k);
}
__device__ __forceinline__ void gld16(const void* g, void* l) {
    __builtin_amdgcn_global_load_lds(
        (const __attribute__((address_space(1))) void*)g,
        (__attribute__((address_space(3))) void*)l, 16, 0, 0);
}

// ---------- fused: fp32->fp8 cvt + stat zeroing + out zeroing + member lists
// R16: also records picls[j] = position of sample j inside its class's member
// list, so the gemm epilogue can write positives COMPACTLY (posc[row][slot])
// and pos_final reads them with one coalesced wave-load instead of a 64-line
// scatter-gather through the 32MB pairsim matrix.
__global__ __launch_bounds__(256) void cvt_build(const float* __restrict__ in,
                                                 unsigned* __restrict__ out8,   // 4 fp8 per uint
                                                 float* __restrict__ statz,     // negsum+negmax
                                                 const int* __restrict__ labels,
                                                 int* __restrict__ members,
                                                 int* __restrict__ classCount,
                                                 int* __restrict__ picls,
                                                 float* __restrict__ loss_out,
                                                 int n4, int nz4, int ncvt, int Bn) {
    __shared__ int cnt;
    const int bid = blockIdx.x;
    const int t = threadIdx.x;
    if (bid < ncvt) {
        int i = bid * 256 + t;
        if (bid == 0 && t == 0) loss_out[0] = 0.0f;
        if (i < nz4) ((float4*)statz)[i] = make_float4(0.f, 0.f, 0.f, 0.f);
        if (i >= n4) return;
        float4 v = ((const float4*)in)[i];
        int w = __builtin_amdgcn_cvt_pk_fp8_f32(v.x, v.y, 0, false);   // bytes 0,1
        w = __builtin_amdgcn_cvt_pk_fp8_f32(v.z, v.w, w, true);        // bytes 2,3
        out8[i] = (unsigned)w;
    } else {
        const int c = bid - ncvt;
        if (t == 0) cnt = 0;
        __syncthreads();
        for (int j = t; j < Bn; j += 256) {
            if (labels[j] == c) {
                int p = atomicAdd(&cnt, 1);
                if (p < MEMSTRIDE) members[c * MEMSTRIDE + p] = j;
                picls[j] = p;
            }
        }
        __syncthreads();
        if (t == 0) classCount[c] = (cnt < MEMSTRIDE) ? cnt : MEMSTRIDE;
    }
}

// ---------- GEMM, FP8 e4m3, 128x64 tiles (grid 1056 -> ~4 blocks/CU) --------
// R14's proven dbuf gld_lds discipline (R15's 3-deep counted-vmcnt pipeline
// REGRESSED +10us: at 4 blocks/CU the inter-block m114 overlap already hides
// the per-stage vmcnt(0) drain, and the extra barriers/sched pins only cost).
// Epilogue change only: positives go to compact posc[row][picls[col]] (2MB,
// L2-resident) instead of pairsim[row][col] (32MB scatter).
__global__ __launch_bounds__(256, 4) void gemm_fused(const unsigned char* __restrict__ fb8,
                                                     const int* __restrict__ labels,
                                                     const int* __restrict__ picls,
                                                     float* __restrict__ negsum,
                                                     unsigned* __restrict__ negmax,
                                                     unsigned short* __restrict__ posc,
                                                     int Bn, int Dn) {
    __shared__ __align__(16) unsigned char As[2][8192];   // [128 rows][64B] dbuf
    __shared__ __align__(16) unsigned char Bs[2][4096];   // [64 rows][64B] dbuf
    __shared__ int Lrow[128], Lcol[64];
    __shared__ int Prow[128], Pcol[64];

    // bid -> (by, c64): band by starts at by*(by+1), has 2*by+2 tiles
    const int bid = blockIdx.x;
    int by = (int)(sqrtf((float)bid + 0.25f) - 0.5f);
    while ((by + 1) * (by + 2) <= bid) by++;
    while (by * (by + 1) > bid) by--;
    const int c64 = bid - by * (by + 1);
    const int gcb = c64 * 64;                 // global col base
    const bool mirror = (gcb < by * 128);     // strictly left of diag block

    const int t = threadIdx.x;
    const int wave = t >> 6, lane = t & 63;
    const int quad = lane >> 4, m16 = lane & 15;

    if (t < 128) {
        Lrow[t] = labels[by * 128 + t];
        Prow[t] = picls[by * 128 + t];
    } else if (t < 192) {
        Lcol[t - 128] = labels[gcb + (t - 128)];
        Pcol[t - 128] = picls[gcb + (t - 128)];
    }

    // staging: A rows r=t>>2 and r+64 (slot a=t&3); B rows r (64 rows, 1 granule).
    // Global fetch XOR-swizzled so linear-LDS ds_read_b64 frags are conflict-free.
    const int r = t >> 2, a = t & 3;
    const int gofs = ((2 * a) ^ (r & 6)) * 8;
    const unsigned char* gA0 = fb8 + (size_t)(by * 128 + r) * Dn + gofs;
    const unsigned char* gA1 = gA0 + (size_t)64 * Dn;
    const unsigned char* gB0 = fb8 + (size_t)(gcb + r) * Dn + gofs;
    const int lb = t * 16;   // bytes

    floatx4 acc[2][4];
#pragma unroll
    for (int i = 0; i < 2; i++)
#pragma unroll
        for (int j = 0; j < 4; j++) acc[i][j] = (floatx4){0.f, 0.f, 0.f, 0.f};

    // fragment reads: row stride 64B; logical half-chunk hc = quad + 4*kstep
    // lives at physical (hc ^ (m16&6))*8
    const int fragA = (wave * 32 + m16) * 64;
    const int fragB = m16 * 64;
    const int sw = m16 & 6;
    const int sK0 = (quad ^ sw) * 8;
    const int sK1 = ((quad + 4) ^ sw) * 8;

    const int NS = Dn / 64;   // 16 stages

    // prologue: DMA(0) -> buf 0 (3 gld16/thread)
    gld16(gA0, &As[0][lb]);
    gld16(gA1, &As[0][4096 + lb]);
    gld16(gB0, &Bs[0][lb]);
    __syncthreads();   // drains DMA(0); labels visible

    for (int s = 0; s < NS; s++) {
        if (s + 1 < NS) {
            const int ko = (s + 1) * 64;
            const int nb = (s + 1) & 1;
            gld16(gA0 + ko, &As[nb][lb]);
            gld16(gA1 + ko, &As[nb][4096 + lb]);
            gld16(gB0 + ko, &Bs[nb][lb]);
        }
        __builtin_amdgcn_sched_barrier(0);   // pin DMA issue before compute

        const unsigned char* as_ = &As[s & 1][0];
        const unsigned char* bs_ = &Bs[s & 1][0];
        long af[2], bfr[4];
        // k-step 0
#pragma unroll
        for (int i = 0; i < 2; i++) af[i]  = *(const long*)(as_ + fragA + i * 1024 + sK0);
#pragma unroll
        for (int j = 0; j < 4; j++) bfr[j] = *(const long*)(bs_ + fragB + j * 1024 + sK0);
#pragma unroll
        for (int i = 0; i < 2; i++)
#pragma unroll
            for (int j = 0; j < 4; j++)
                acc[i][j] = __builtin_amdgcn_mfma_f32_16x16x32_fp8_fp8(af[i], bfr[j], acc[i][j], 0, 0, 0);
        // k-step 1
#pragma unroll
        for (int i = 0; i < 2; i++) af[i]  = *(const long*)(as_ + fragA + i * 1024 + sK1);
#pragma unroll
        for (int j = 0; j < 4; j++) bfr[j] = *(const long*)(bs_ + fragB + j * 1024 + sK1);
#pragma unroll
        for (int i = 0; i < 2; i++)
#pragma unroll
            for (int j = 0; j < 4; j++)
                acc[i][j] = __builtin_amdgcn_mfma_f32_16x16x32_fp8_fp8(af[i], bfr[j], acc[i][j], 0, 0, 0);

        __syncthreads();   // drains DMA(s+1): issued one full stage ago
    }

    // ----- single-pass epilogue (C/D: col = m16 + j*16, row = quad*4+rr + i*16)
    int cl[4], gc[4], pc_[4];
#pragma unroll
    for (int j = 0; j < 4; j++) {
        cl[j] = Lcol[j * 16 + m16];
        gc[j] = gcb + j * 16 + m16;
        pc_[j] = Pcol[j * 16 + m16];
    }

    float nsm[4] = {0.f, 0.f, 0.f, 0.f};
    float nmm[4] = {-INFINITY, -INFINITY, -INFINITY, -INFINITY};

#pragma unroll
    for (int i = 0; i < 2; i++) {
#pragma unroll
        for (int rr = 0; rr < 4; rr++) {
            const int rowl = wave * 32 + i * 16 + quad * 4 + rr;
            const int rl = Lrow[rowl];
            const int gr = by * 128 + rowl;
            float ns = 0.f, nm = -INFINITY;
#pragma unroll
            for (int j = 0; j < 4; j++) {
                const float s = acc[i][j][rr];
                if (cl[j] != rl) {
                    const float e = __expf(40.f * s);
                    ns += e;
                    nm = fmaxf(nm, s);
                    nsm[j] += e;
                    nmm[j] = fmaxf(nmm[j], s);
                } else if ((gr != gc[j]) & (s < ONE_M_EPS)) {
                    const unsigned short v = f2bf(s);
                    if (pc_[j] < MEMSTRIDE)
                        posc[(size_t)gr * MEMSTRIDE + pc_[j]] = v;
                    if (mirror) {
                        const int pr_ = Prow[rowl];
                        if (pr_ < MEMSTRIDE)
                            posc[(size_t)gc[j] * MEMSTRIDE + pr_] = v;
                    }
                }
            }
#pragma unroll
            for (int o = 8; o; o >>= 1) {
                ns += __shfl_down(ns, o, 64);
                nm = fmaxf(nm, __shfl_down(nm, o, 64));
            }
            if (m16 == 0) {
                atomicAdd(negsum + gr, ns);
                atomicMax(negmax + gr, fkey(nm));
            }
        }
    }
    if (mirror) {   // column stats feed rows gcb.. (only for strictly-left tiles)
#pragma unroll
        for (int j = 0; j < 4; j++) {
            float v = nsm[j], m = nmm[j];
            v += __shfl_down(v, 16, 64);
            m = fmaxf(m, __shfl_down(m, 16, 64));
            v += __shfl_down(v, 32, 64);
            m = fmaxf(m, __shfl_down(m, 32, 64));
            if (quad == 0) {
                atomicAdd(negsum + gc[j], v);
                atomicMax(negmax + gc[j], fkey(m));
            }
        }
    }
}

// ---------- positives + per-row loss + mean: 1 row per WAVE (R16) -----------
// Old: 1 block/CU, 1 wave/SIMD, 4 rows SEQUENTIAL per wave, 64-line scattered
// pairsim gather per row -> pure latency serial chain with zero TLP. New:
// grid Bn/4=1024 blocks (4 blocks/CU, 16 waves/CU), 1 row per wave, positives
// read as ONE coalesced 128B load from the compact posc row. Self-pair is
// skipped by slot index (picls[r]) -> no members[] gather at all.
__global__ __launch_bounds__(256) void pos_final(const unsigned short* __restrict__ posc,
                                                 const int* __restrict__ labels,
                                                 const int* __restrict__ classCount,
                                                 const int* __restrict__ picls,
                                                 const unsigned* __restrict__ negmax,
                                                 const float* __restrict__ negsum,
                                                 float* __restrict__ out, int Bn) {
    __shared__ float part[4];
    const int t = threadIdx.x;
    const int wave = t >> 6, lane = t & 63;
    const int r = blockIdx.x * 4 + wave;

    const int lab = labels[r];
    const int selfp = picls[r];
    const float mx = fdec(negmax[r]);
    const float nsum = negsum[r];
    const int n = classCount[lab];
    const unsigned short* prow = posc + (size_t)r * MEMSTRIDE;

    float ps = 0.f, pc = 0.f;
    for (int j = lane; j < n; j += 64) {
        if (j != selfp) {
            const float s = bf2f(prow[j]);
            if ((s - MARGIN_C) < mx) {
                ps += __expf(-2.f * s);
                pc += 1.f;
            }
        }
    }
#pragma unroll
    for (int o = 32; o; o >>= 1) {
        ps += __shfl_down(ps, o, 64);
        pc += __shfl_down(pc, o, 64);
    }
    float wacc = 0.f;
    if (lane == 0) {
        const int nneg = Bn - n;
        if (nneg >= 1 && pc >= 0.5f) {
            float pl = 0.5f * logf((ps + expf(-2.f * 0.501f)) / (pc + 1.f));
            float nl = (1.f / 40.f) * logf((nsum + expf(40.f * 0.531f)) / ((float)nneg + 1.f));
            wacc = logf(5.33f + expf(pl + nl));
        }
        part[wave] = wacc;
    }
    __syncthreads();
    if (t == 0) {
        atomicAdd(out, (part[0] + part[1] + part[2] + part[3]) / (float)Bn);
    }
}

extern "C" void kernel_launch(void* const* d_in, const int* in_sizes, int n_in,
                              void* d_out, int out_size, void* d_ws, size_t ws_size,
                              hipStream_t stream) {
    const float* feats = (const float*)d_in[0];
    const int* labels  = (const int*)d_in[1];
    float* out = (float*)d_out;

    const int Bn = in_sizes[1];           // 4096
    const int Dn = in_sizes[0] / Bn;      // 1024

    unsigned char* fb8 = (unsigned char*)d_ws;                  // fp8 feats [Bn][Dn]
    float* stats    = (float*)(fb8 + (size_t)Bn * Dn);
    float* negsum   = stats;                                    // [Bn]
    unsigned* negmax = (unsigned*)(stats + Bn);                 // [Bn] keyed
    int* classCount = (int*)(stats + 2 * Bn);                   // [NCLS]
    int* members    = classCount + NCLS;                        // [NCLS][MEMSTRIDE]
    int* picls      = members + NCLS * MEMSTRIDE;               // [Bn] pos-in-class
    unsigned short* posc = (unsigned short*)(picls + Bn);       // [Bn][MEMSTRIDE] compact positives

    const int n4   = (Bn * Dn) / 4;
    const int nz4  = (2 * Bn) / 4;        // zero negsum+negmax
    const int ncvt = (n4 + 255) / 256;
    cvt_build<<<ncvt + NCLS, 256, 0, stream>>>(feats, (unsigned*)fb8, stats, labels,
                                               members, classCount, picls, out,
                                               n4, nz4, ncvt, Bn);

    const int nt = Bn / 128;              // 32 bands
    const int ngrid = nt * (nt + 1);      // 1056 tiles of 128x64
    gemm_fused<<<ngrid, 256, 0, stream>>>(fb8, labels, picls, negsum, negmax, posc, Bn, Dn);

    pos_final<<<Bn / 4, 256, 0, stream>>>(posc, labels, classCount, picls,
                                          negmax, negsum, out, Bn);
}